// Round 4
// baseline (247.933 us; speedup 1.0000x reference)
//
#include <hip/hip_runtime.h>

typedef unsigned short u16;
typedef unsigned int u32;
typedef __bf16 bf16x8 __attribute__((ext_vector_type(8)));
typedef float f32x4 __attribute__((ext_vector_type(4)));
typedef short s16x4 __attribute__((ext_vector_type(4)));

#define AS1 __attribute__((address_space(1)))
#define AS3 __attribute__((address_space(3)))

__device__ __forceinline__ f32x4 mfma16(bf16x8 a, bf16x8 b, f32x4 c) {
    return __builtin_amdgcn_mfma_f32_16x16x32_bf16(a, b, c, 0, 0, 0);
}
// K=16 shape: B-operand layout == C/D layout (transpose-free PV)
__device__ __forceinline__ f32x4 mfma16k16(s16x4 a, s16x4 b, f32x4 c) {
    return __builtin_amdgcn_mfma_f32_16x16x16bf16_1k(a, b, c, 0, 0, 0);
}

__device__ __forceinline__ u16 f2bf(float f) {
    return __builtin_bit_cast(u16, (__bf16)f);
}

__device__ __forceinline__ void gld16(const u16* g, u16* l) {
    __builtin_amdgcn_global_load_lds((AS1 void*)g, (AS3 void*)l, 16, 0, 0);
}

// Raw barrier: drain LDS ops only; global prefetch loads stay in flight (T4).
__device__ __forceinline__ void barrier_nodrain() {
    asm volatile("s_waitcnt lgkmcnt(0)" ::: "memory");
    __builtin_amdgcn_s_barrier();
    asm volatile("" ::: "memory");
}

// ---------------- fused fp32 -> bf16 conversion ----------------
__global__ __launch_bounds__(256) void cvt_all(const float* __restrict__ q, const float* __restrict__ k,
                                               const float* __restrict__ v, const float* __restrict__ wq,
                                               const float* __restrict__ wk, const float* __restrict__ wv,
                                               const float* __restrict__ wo, u16* __restrict__ qo,
                                               u16* __restrict__ ko, u16* __restrict__ vo,
                                               u16* __restrict__ wqo, u16* __restrict__ wko,
                                               u16* __restrict__ wvo, u16* __restrict__ woo) {
    const int y = blockIdx.y;
    const float* x; u16* o; int n;
    switch (y) {
        case 0: x = q; o = qo; n = 4 << 20; break;
        case 1: x = k; o = ko; n = 4 << 20; break;
        case 2: x = v; o = vo; n = 4 << 20; break;
        case 3: x = wq; o = wqo; n = 1 << 20; break;
        case 4: x = wk; o = wko; n = 1 << 20; break;
        case 5: x = wv; o = wvo; n = 1 << 20; break;
        default: x = wo; o = woo; n = 1 << 20; break;
    }
    int i = (blockIdx.x * 256 + threadIdx.x) * 4;
    if (i >= n) return;
    float4 vv = *(const float4*)(x + i);
    u32 lo = (u32)f2bf(vv.x) | ((u32)f2bf(vv.y) << 16);
    u32 hi = (u32)f2bf(vv.z) | ((u32)f2bf(vv.w) << 16);
    *(uint2*)(o + i) = make_uint2(lo, hi);
}

// ---------------- GEMM: C[.,N] = A[.,K] @ Bt[N,K]^T ----------------
template <int BM, int BN, bool BF16OUT>
__device__ __forceinline__ void gemm_core(const u16* __restrict__ A, const u16* __restrict__ Bt,
                                          void* __restrict__ Cp, int K, int N, int m0, int n0,
                                          float oscale) {
    constexpr int WROWS = BM / 64;        // 2 (128x128) or 1 (64x128)
    constexpr int WCOLS = 4 / WROWS;      // 2 or 4
    constexpr int BFR = BN / WCOLS / 16;  // 4 or 2
    __shared__ __align__(16) u16 As[BM * 32];
    __shared__ __align__(16) u16 Bs[BN * 32];
    const int tid = threadIdx.x;
    const int lane = tid & 63, wave = tid >> 6;
    const int l16 = lane & 15, q4 = lane >> 4;
    const int wm = (wave / WCOLS) * 64, wn = (wave % WCOLS) * (BFR * 16);

    const f32x4 fz = {0.f, 0.f, 0.f, 0.f};
    f32x4 acc[4][BFR];
#pragma unroll
    for (int i = 0; i < 4; ++i)
#pragma unroll
        for (int j = 0; j < BFR; ++j) acc[i][j] = fz;

    const int rseg = lane >> 2;
    const int ck = ((lane & 3) ^ ((lane >> 3) & 3)) * 8;  // swizzled k-chunk
    const u16* Ag = A + (size_t)(m0 + wave * 16 + rseg) * K + ck;
    const u16* Bg = Bt + (size_t)(n0 + wave * 16 + rseg) * K + ck;

    const int swz = (q4 ^ ((l16 & 7) >> 1)) * 8;

    for (int k0 = 0; k0 < K; k0 += 32) {
        __syncthreads();
#pragma unroll
        for (int p = 0; p < BM / 64; ++p)
            gld16(Ag + (size_t)p * 64 * K + k0, As + p * 2048 + wave * 512);
#pragma unroll
        for (int p = 0; p < BN / 64; ++p)
            gld16(Bg + (size_t)p * 64 * K + k0, Bs + p * 2048 + wave * 512);
        __syncthreads();
        bf16x8 af[4], bfr[BFR];
#pragma unroll
        for (int i = 0; i < 4; ++i)
            af[i] = *(const bf16x8*)&As[(wm + i * 16 + l16) * 32 + swz];
#pragma unroll
        for (int j = 0; j < BFR; ++j)
            bfr[j] = *(const bf16x8*)&Bs[(wn + j * 16 + l16) * 32 + swz];
#pragma unroll
        for (int i = 0; i < 4; ++i)
#pragma unroll
            for (int j = 0; j < BFR; ++j) acc[i][j] = mfma16(af[i], bfr[j], acc[i][j]);
    }

#pragma unroll
    for (int i = 0; i < 4; ++i) {
        const int row = m0 + wm + i * 16 + q4 * 4;
#pragma unroll
        for (int j = 0; j < BFR; ++j) {
            const int col = n0 + wn + j * 16 + l16;
#pragma unroll
            for (int r = 0; r < 4; ++r) {
                const float vr = acc[i][j][r] * oscale;
                if constexpr (BF16OUT)
                    ((u16*)Cp)[(size_t)(row + r) * N + col] = f2bf(vr);
                else
                    ((float*)Cp)[(size_t)(row + r) * N + col] = vr;
            }
        }
    }
}

// z=0: Q = query@wq^T (pre-scaled by 0.125*log2e); z=1: K = key@wk^T;
// z=2: Vt = wv @ value^T -> VtAll[h*64+dv][b*2048+s]
// T1: XCD-aware swizzle for z in {0,1}: XCD c gets 32 contiguous tiles
// (4 A-panels x all 8 B-panels -> 3 MB working set, fits 4 MB L2).
// z=2 keeps identity: n%8 already gives disjoint B-panels per XCD.
__global__ __launch_bounds__(256) void gemm_qkv(const u16* __restrict__ qb, const u16* __restrict__ kb,
                                                const u16* __restrict__ vb, const u16* __restrict__ wqb,
                                                const u16* __restrict__ wkb, const u16* __restrict__ wvb,
                                                u16* __restrict__ Qp, u16* __restrict__ Kp,
                                                u16* __restrict__ VtAll) {
    const int z = blockIdx.y;
    int x = blockIdx.x;
    if (z != 2) x = (x & 7) * 32 + (x >> 3);  // bijective: 256 % 8 == 0
    const u16 *A, *Bt;
    u16* C;
    int N, m0, n0;
    float sc = 1.0f;
    if (z == 0) {
        A = qb; Bt = wqb; C = Qp; N = 1024; m0 = (x >> 3) * 128; n0 = (x & 7) * 128;
        sc = 0.18033688011112042f;  // (1/sqrt(64)) * log2(e)
    } else if (z == 1) {
        A = kb; Bt = wkb; C = Kp; N = 1024; m0 = (x >> 3) * 128; n0 = (x & 7) * 128;
    } else {
        A = wvb; Bt = vb; C = VtAll; N = 4096; m0 = (x >> 5) * 128; n0 = (x & 31) * 128;
    }
    gemm_core<128, 128, true>(A, Bt, C, 1024, N, m0, n0, sc);
}

__global__ __launch_bounds__(256) void gemm_out(const u16* __restrict__ ctx,
                                                const u16* __restrict__ wob,
                                                float* __restrict__ out) {
    // T1 swizzle: XCD c gets 64 contiguous tiles (8 m-panels x all 8 n) = 3 MB L2 set
    const int xo = (blockIdx.x & 7) * 64 + (blockIdx.x >> 3);  // bijective: 512 % 8 == 0
    gemm_core<64, 128, false>(ctx, wob, out, 1024, 1024, (xo >> 3) * 64, (xo & 7) * 128, 1.0f);
}

// ---------------- Flash attention: 4-wave blocks, 4 independent blocks/CU ----------------
// Round-3 lesson: 8-wave blocks barrier-lock all resident waves into the same
// QK(MFMA)/exp(VALU)/PV(MFMA) phase -> pipes serialize (MfmaUtil 43 + VALUBusy 41,
// ~2000 idle cyc/region). Fix topology, not schedule: 256-thr blocks (4 waves x 16
// q-rows = 64 q-rows/block), grid 1024 -> 4 barrier-INDEPENDENT blocks/CU (LDS
// 36.9 KB x 4 = 147 KB). Blocks drift into anti-phase: one block's exp fills
// another's matrix stalls. Same 16 waves/CU; staging/compute semantics unchanged
// (each thread stages 2x16B of K and V via p-loop; vswap=(tid>>6)&1 is p-invariant).
// T1: XCD swizzle, qt innermost -> each XCD owns 4 whole (b,h) groups (2 MB L2 set).
__global__ __launch_bounds__(256, 4) void flash_attn(const u16* __restrict__ Qp,
                                                     const u16* __restrict__ Kp,
                                                     const u16* __restrict__ VtAll,
                                                     u16* __restrict__ Ctx) {
    constexpr int D = 1024, SS = 2048, LD = 72;
    __shared__ __align__(16) u16 Ks[2][64 * LD];   // [buf][s_row][dk]
    __shared__ __align__(16) u16 Vts[2][64 * LD];  // [buf][dv][s], 8B sub-chunk swizzled

    const int tid = threadIdx.x;
    const int lane = tid & 63, wave = tid >> 6;  // 4 waves
    const int l16 = lane & 15, q4 = lane >> 4;

    const int nb = blockIdx.x;                    // 1024 blocks, 1D
    const int orig = (nb & 7) * 128 + (nb >> 3);  // bijective: 1024 % 8 == 0
    const int qt = orig & 31, h = (orig >> 5) & 15, b = orig >> 9;
    const int q0 = qt * 64 + wave * 16;

    bf16x8 qf[2];
    {
        const u16* Qb = Qp + (size_t)(b * SS + q0 + l16) * D + h * 64;
        qf[0] = *(const bf16x8*)(Qb + q4 * 8);
        qf[1] = *(const bf16x8*)(Qb + 32 + q4 * 8);
    }

    const f32x4 fz = {0.f, 0.f, 0.f, 0.f};
    f32x4 ot[4], lacc = fz;
#pragma unroll
    for (int dt = 0; dt < 4; ++dt) ot[dt] = fz;

    s16x4 onesA;
    onesA[0] = onesA[1] = onesA[2] = onesA[3] = (short)0x3F80;  // bf16 1.0

    // staging: 256 threads x two uint4 (p=0: rows 0..31, p=1: rows 32..63)
    const int sr = tid >> 3;           // 0..31
    const int scol = (tid & 7) * 8;    // 8-elem (16B) chunk
    const int vswap = (tid >> 6) & 1;  // == (dv>>3)&1 for both staged rows (row+32 keeps bit3)
    const int swV = (l16 >> 3) & 1;    // read-side sub-chunk swizzle key
    const u16* Kg = Kp + (size_t)(b * SS + sr) * D + h * 64 + scol;
    const u16* Vg = VtAll + (size_t)(h * 64 + sr) * 4096 + b * SS + scol;

    uint4 kv[2], vv[2];
    auto prefetch = [&](int kt) {
#pragma unroll
        for (int p = 0; p < 2; ++p) {
            kv[p] = *(const uint4*)(Kg + (size_t)(kt + p * 32) * D);
            vv[p] = *(const uint4*)(Vg + (size_t)p * 32 * 4096 + kt);
        }
    };
    auto stage = [&](int buf) {
#pragma unroll
        for (int p = 0; p < 2; ++p) {
            uint4 w = vswap ? make_uint4(vv[p].z, vv[p].w, vv[p].x, vv[p].y) : vv[p];
            *(uint4*)&Ks[buf][(sr + p * 32) * LD + scol] = kv[p];
            *(uint4*)&Vts[buf][(sr + p * 32) * LD + scol] = w;
        }
    };

    prefetch(0);
    for (int kt = 0; kt < SS; kt += 64) {
        const int buf = (kt >> 6) & 1;
        stage(buf);
        const int nk = (kt + 64 < SS) ? kt + 64 : 0;  // wrap: harmless dead load
        prefetch(nk);
        barrier_nodrain();

        // S^T = K·Q^T (exp2 domain; Q pre-scaled by 0.125*log2e)
        f32x4 st[4];
        __builtin_amdgcn_s_setprio(1);
#pragma unroll
        for (int nt = 0; nt < 4; ++nt) {
            const bf16x8 ka = *(const bf16x8*)&Ks[buf][(nt * 16 + l16) * LD + q4 * 8];
            const bf16x8 kb2 = *(const bf16x8*)&Ks[buf][(nt * 16 + l16) * LD + 32 + q4 * 8];
            f32x4 s = mfma16(ka, qf[0], fz);
            st[nt] = mfma16(kb2, qf[1], s);
        }
        __builtin_amdgcn_s_setprio(0);

        // P^T = exp2(S^T), in-register (K=16 B-frag layout)
        s16x4 p[4];
#pragma unroll
        for (int nt = 0; nt < 4; ++nt) {
#pragma unroll
            for (int r = 0; r < 4; ++r)
                p[nt][r] = (short)f2bf(__builtin_amdgcn_exp2f(st[nt][r]));
        }

        // O^T += V^T·P^T ; l via ones-MFMA (every reg = l[q=l16])
        __builtin_amdgcn_s_setprio(1);
#pragma unroll
        for (int nt = 0; nt < 4; ++nt) {
#pragma unroll
            for (int dt = 0; dt < 4; ++dt) {
                const s16x4 va =
                    *(const s16x4*)&Vts[buf][(dt * 16 + l16) * LD + ((nt * 4 + q4) ^ swV) * 4];
                ot[dt] = mfma16k16(va, p[nt], ot[dt]);
            }
            lacc = mfma16k16(onesA, p[nt], lacc);
        }
        __builtin_amdgcn_s_setprio(0);
    }

    // normalize + direct bf16 ctx write (lacc broadcast: all regs hold l[q=l16])
    {
        const float inv = 1.f / lacc[0];
        u16* Cb = Ctx + (size_t)(b * SS + q0 + l16) * D + h * 64 + q4 * 4;
#pragma unroll
        for (int dt = 0; dt < 4; ++dt) {
            s16x4 w;
#pragma unroll
            for (int r = 0; r < 4; ++r) w[r] = (short)f2bf(ot[dt][r] * inv);
            *(s16x4*)(Cb + dt * 16) = w;  // O[q][dv], dv = dt*16 + q4*4 + r
        }
    }
}

extern "C" void kernel_launch(void* const* d_in, const int* in_sizes, int n_in,
                              void* d_out, int out_size, void* d_ws, size_t ws_size,
                              hipStream_t stream) {
    const float* query = (const float*)d_in[0];
    const float* key   = (const float*)d_in[1];
    const float* value = (const float*)d_in[2];
    const float* w_q   = (const float*)d_in[3];
    const float* w_k   = (const float*)d_in[4];
    const float* w_v   = (const float*)d_in[5];
    const float* w_o   = (const float*)d_in[6];
    float* out = (float*)d_out;

    const size_t MEG = 1024 * 1024;
    if (ws_size < 64 * MEG) return;  // layout needs 64 MiB
    u16* ws = (u16*)d_ws;
    u16* qb    = ws;
    u16* kb    = ws + 4 * MEG;
    u16* vb    = ws + 8 * MEG;
    u16* wqb   = ws + 12 * MEG;
    u16* wkb   = ws + 13 * MEG;
    u16* wvb   = ws + 14 * MEG;
    u16* wob   = ws + 15 * MEG;  // live until gemm_out
    u16* Qp    = ws + 16 * MEG;
    u16* Kp    = ws + 20 * MEG;
    u16* VtAll = ws + 24 * MEG;
    u16* ctx   = ws + 28 * MEG;  // ends at 32 MEG u16 = 64 MiB

    cvt_all<<<dim3(4096, 7), 256, 0, stream>>>(query, key, value, w_q, w_k, w_v, w_o,
                                               qb, kb, vb, wqb, wkb, wvb, wob);
    gemm_qkv<<<dim3(256, 3), 256, 0, stream>>>(qb, kb, vb, wqb, wkb, wvb, Qp, Kp, VtAll);
    flash_attn<<<dim3(1024), 256, 0, stream>>>(Qp, Kp, VtAll, ctx);
    gemm_out<<<dim3(512), 256, 0, stream>>>(ctx, wob, out);
}

// Round 5
// 241.655 us; speedup vs baseline: 1.0260x; 1.0260x over previous
//
#include <hip/hip_runtime.h>

typedef unsigned short u16;
typedef unsigned int u32;
typedef __bf16 bf16x8 __attribute__((ext_vector_type(8)));
typedef float f32x4 __attribute__((ext_vector_type(4)));
typedef short s16x4 __attribute__((ext_vector_type(4)));

#define AS1 __attribute__((address_space(1)))
#define AS3 __attribute__((address_space(3)))

__device__ __forceinline__ f32x4 mfma16(bf16x8 a, bf16x8 b, f32x4 c) {
    return __builtin_amdgcn_mfma_f32_16x16x32_bf16(a, b, c, 0, 0, 0);
}
// K=16 shape: B-operand layout == C/D layout (transpose-free PV)
__device__ __forceinline__ f32x4 mfma16k16(s16x4 a, s16x4 b, f32x4 c) {
    return __builtin_amdgcn_mfma_f32_16x16x16bf16_1k(a, b, c, 0, 0, 0);
}

__device__ __forceinline__ u16 f2bf(float f) {
    return __builtin_bit_cast(u16, (__bf16)f);
}

__device__ __forceinline__ void gld16(const u16* g, u16* l) {
    __builtin_amdgcn_global_load_lds((AS1 void*)g, (AS3 void*)l, 16, 0, 0);
}

// 8x fp32 -> 8x bf16 packed (compiler emits v_cvt_pk_bf16_f32 pairs)
__device__ __forceinline__ uint4 pack8(float4 a, float4 b) {
    return make_uint4((u32)f2bf(a.x) | ((u32)f2bf(a.y) << 16),
                      (u32)f2bf(a.z) | ((u32)f2bf(a.w) << 16),
                      (u32)f2bf(b.x) | ((u32)f2bf(b.y) << 16),
                      (u32)f2bf(b.z) | ((u32)f2bf(b.w) << 16));
}

// Raw barrier: drain LDS ops only; global prefetch loads stay in flight (T4).
__device__ __forceinline__ void barrier_nodrain() {
    asm volatile("s_waitcnt lgkmcnt(0)" ::: "memory");
    __builtin_amdgcn_s_barrier();
    asm volatile("" ::: "memory");
}

// ---------------- GEMM: C[.,N] = A[.,K] @ Bt[N,K]^T ----------------
// AF32/BF32: operand is fp32 in global; reg-stage with fp32->bf16 conversion
// (cvt fused into GEMM -- eliminates the separate cvt_all pass). Prefetch of
// k-step k+1 issues after the second barrier so global latency hides under
// the MFMA phase (T14). bf16 operands keep global_load_lds staging.
template <int BM, int BN, bool BF16OUT, bool AF32, bool BF32>
__device__ __forceinline__ void gemm_core(const void* __restrict__ Apv, const void* __restrict__ Btv,
                                          void* __restrict__ Cp, int K, int N, int m0, int n0,
                                          float oscale) {
    constexpr int WROWS = BM / 64;        // 2 (128x128) or 1 (64x128)
    constexpr int WCOLS = 4 / WROWS;      // 2 or 4
    constexpr int BFR = BN / WCOLS / 16;  // 4 or 2
    constexpr int PA = BM / 64, PB = BN / 64;
    __shared__ __align__(16) u16 As[BM * 32];
    __shared__ __align__(16) u16 Bs[BN * 32];
    const int tid = threadIdx.x;
    const int lane = tid & 63, wave = tid >> 6;
    const int l16 = lane & 15, q4 = lane >> 4;
    const int wm = (wave / WCOLS) * 64, wn = (wave % WCOLS) * (BFR * 16);

    const f32x4 fz = {0.f, 0.f, 0.f, 0.f};
    f32x4 acc[4][BFR];
#pragma unroll
    for (int i = 0; i < 4; ++i)
#pragma unroll
        for (int j = 0; j < BFR; ++j) acc[i][j] = fz;

    const int rseg = lane >> 2;
    const int ck = ((lane & 3) ^ ((lane >> 3) & 3)) * 8;  // swizzled k-chunk
    const size_t arow = (size_t)(m0 + wave * 16 + rseg) * K + ck;
    const size_t brow = (size_t)(n0 + wave * 16 + rseg) * K + ck;
    const u16* Ag = (const u16*)Apv + arow;
    const float* Af = (const float*)Apv + arow;
    const u16* Bg = (const u16*)Btv + brow;
    const float* Bf = (const float*)Btv + brow;

    const int swz = (q4 ^ ((l16 & 7) >> 1)) * 8;

    float4 pfa[PA][2], pfb[PB][2];
    auto prefetch = [&](int k0) {
        if constexpr (AF32) {
#pragma unroll
            for (int p = 0; p < PA; ++p) {
                pfa[p][0] = *(const float4*)(Af + (size_t)p * 64 * K + k0);
                pfa[p][1] = *(const float4*)(Af + (size_t)p * 64 * K + k0 + 4);
            }
        }
        if constexpr (BF32) {
#pragma unroll
            for (int p = 0; p < PB; ++p) {
                pfb[p][0] = *(const float4*)(Bf + (size_t)p * 64 * K + k0);
                pfb[p][1] = *(const float4*)(Bf + (size_t)p * 64 * K + k0 + 4);
            }
        }
    };
    prefetch(0);

    for (int k0 = 0; k0 < K; k0 += 32) {
        __syncthreads();
        if constexpr (AF32) {
#pragma unroll
            for (int p = 0; p < PA; ++p)
                *(uint4*)&As[p * 2048 + wave * 512 + lane * 8] = pack8(pfa[p][0], pfa[p][1]);
        } else {
#pragma unroll
            for (int p = 0; p < PA; ++p)
                gld16(Ag + (size_t)p * 64 * K + k0, As + p * 2048 + wave * 512);
        }
        if constexpr (BF32) {
#pragma unroll
            for (int p = 0; p < PB; ++p)
                *(uint4*)&Bs[p * 2048 + wave * 512 + lane * 8] = pack8(pfb[p][0], pfb[p][1]);
        } else {
#pragma unroll
            for (int p = 0; p < PB; ++p)
                gld16(Bg + (size_t)p * 64 * K + k0, Bs + p * 2048 + wave * 512);
        }
        __syncthreads();
        if (k0 + 32 < K) prefetch(k0 + 32);  // latency hides under MFMA phase (T14)

        bf16x8 af[4], bfr[BFR];
#pragma unroll
        for (int i = 0; i < 4; ++i)
            af[i] = *(const bf16x8*)&As[(wm + i * 16 + l16) * 32 + swz];
#pragma unroll
        for (int j = 0; j < BFR; ++j)
            bfr[j] = *(const bf16x8*)&Bs[(wn + j * 16 + l16) * 32 + swz];
#pragma unroll
        for (int i = 0; i < 4; ++i)
#pragma unroll
            for (int j = 0; j < BFR; ++j) acc[i][j] = mfma16(af[i], bfr[j], acc[i][j]);
    }

#pragma unroll
    for (int i = 0; i < 4; ++i) {
        const int row = m0 + wm + i * 16 + q4 * 4;
#pragma unroll
        for (int j = 0; j < BFR; ++j) {
            const int col = n0 + wn + j * 16 + l16;
#pragma unroll
            for (int r = 0; r < 4; ++r) {
                const float vr = acc[i][j][r] * oscale;
                if constexpr (BF16OUT)
                    ((u16*)Cp)[(size_t)(row + r) * N + col] = f2bf(vr);
                else
                    ((float*)Cp)[(size_t)(row + r) * N + col] = vr;
            }
        }
    }
}

// z=0: Q = query@wq^T (pre-scaled by 0.125*log2e); z=1: K = key@wk^T;
// z=2: Vt = wv @ value^T -> VtAll[h*64+dv][b*2048+s]
// Inputs are raw fp32 (conversion fused into staging). T1 XCD swizzle for z in
// {0,1}: XCD c gets 32 contiguous tiles (4 A-panels x all 8 B-panels, ~L2-fit).
__global__ __launch_bounds__(256) void gemm_qkv(const float* __restrict__ q, const float* __restrict__ k,
                                                const float* __restrict__ v, const float* __restrict__ wq,
                                                const float* __restrict__ wk, const float* __restrict__ wv,
                                                u16* __restrict__ Qp, u16* __restrict__ Kp,
                                                u16* __restrict__ VtAll) {
    const int z = blockIdx.y;
    int x = blockIdx.x;
    if (z != 2) x = (x & 7) * 32 + (x >> 3);  // bijective: 256 % 8 == 0
    const float *A, *Bt;
    u16* C;
    int N, m0, n0;
    float sc = 1.0f;
    if (z == 0) {
        A = q; Bt = wq; C = Qp; N = 1024; m0 = (x >> 3) * 128; n0 = (x & 7) * 128;
        sc = 0.18033688011112042f;  // (1/sqrt(64)) * log2(e)
    } else if (z == 1) {
        A = k; Bt = wk; C = Kp; N = 1024; m0 = (x >> 3) * 128; n0 = (x & 7) * 128;
    } else {
        A = wv; Bt = v; C = VtAll; N = 4096; m0 = (x >> 5) * 128; n0 = (x & 31) * 128;
    }
    gemm_core<128, 128, true, true, true>(A, Bt, C, 1024, N, m0, n0, sc);
}

__global__ __launch_bounds__(256) void gemm_out(const u16* __restrict__ ctx,
                                                const float* __restrict__ wo,
                                                float* __restrict__ out) {
    // T1 swizzle: XCD c gets 64 contiguous tiles (8 m-panels x all 8 n) = L2-fit set
    const int xo = (blockIdx.x & 7) * 64 + (blockIdx.x >> 3);  // bijective: 512 % 8 == 0
    // A = ctx (bf16, gld16 staging); B = w_o (fp32, reg-staged with cvt)
    gemm_core<64, 128, false, false, true>(ctx, wo, out, 1024, 1024, (xo >> 3) * 64, (xo & 7) * 128, 1.0f);
}

// ---------------- Flash attention: 8 waves x 16 q-rows (round-3 winner, verbatim) ----
// 512 threads/block, wave owns 16 q-rows. 2 blocks/CU x 8 waves = 4 waves/SIMD.
// Per-tile: stage(buf from regs) -> prefetch(next into regs) -> barrier_nodrain
// (lgkm only; prefetch stays in flight, T4/T14) -> QK, exp, PV.
// Buffer safety: iter t writes buf t&1, last read in compute(t-2), separated by
// barrier(t-1) which every wave passes only after finishing compute(t-2).
// T1: 1D grid + swizzle so each XCD owns 4 whole (h,b) groups -> K/V fetched
// once per XCD (KV+Q working set 3 MB < 4 MB L2). Measured: 56.9 us, MfmaUtil 43.
__global__ __launch_bounds__(512, 4) void flash_attn(const u16* __restrict__ Qp,
                                                     const u16* __restrict__ Kp,
                                                     const u16* __restrict__ VtAll,
                                                     u16* __restrict__ Ctx) {
    constexpr int D = 1024, SS = 2048, LD = 72;
    __shared__ __align__(16) u16 Ks[2][64 * LD];   // [buf][s_row][dk]
    __shared__ __align__(16) u16 Vts[2][64 * LD];  // [buf][dv][s], 8B sub-chunk swizzled

    const int tid = threadIdx.x;
    const int lane = tid & 63, wave = tid >> 6;  // 8 waves
    const int l16 = lane & 15, q4 = lane >> 4;

    const int nb = blockIdx.x;                    // 512 blocks, 1D
    const int orig = (nb & 7) * 64 + (nb >> 3);   // bijective: 512 % 8 == 0
    const int h = (orig >> 4) & 15, b = orig >> 8;
    const int q0 = (orig & 15) * 128 + wave * 16;

    bf16x8 qf[2];
    {
        const u16* Qb = Qp + (size_t)(b * SS + q0 + l16) * D + h * 64;
        qf[0] = *(const bf16x8*)(Qb + q4 * 8);
        qf[1] = *(const bf16x8*)(Qb + 32 + q4 * 8);
    }

    const f32x4 fz = {0.f, 0.f, 0.f, 0.f};
    f32x4 ot[4], lacc = fz;
#pragma unroll
    for (int dt = 0; dt < 4; ++dt) ot[dt] = fz;

    s16x4 onesA;
    onesA[0] = onesA[1] = onesA[2] = onesA[3] = (short)0x3F80;  // bf16 1.0

    // staging: 512 threads x one uint4 each covers a full 64x64 bf16 tile
    const int sr = tid >> 3;           // 0..63
    const int scol = (tid & 7) * 8;    // 8-elem (16B) chunk
    const int vswap = (sr >> 3) & 1;   // == (dv>>3)&1 for the staged row
    const int swV = (l16 >> 3) & 1;    // read-side sub-chunk swizzle key
    const u16* Kg = Kp + (size_t)(b * SS + sr) * D + h * 64 + scol;
    const u16* Vg = VtAll + (size_t)(h * 64 + sr) * 4096 + b * SS + scol;

    uint4 kv, vv;
    auto prefetch = [&](int kt) {
        kv = *(const uint4*)(Kg + (size_t)kt * D);
        vv = *(const uint4*)(Vg + kt);
    };
    auto stage = [&](int buf) {
        uint4 w = vswap ? make_uint4(vv.z, vv.w, vv.x, vv.y) : vv;  // 8B-half swap
        *(uint4*)&Ks[buf][sr * LD + scol] = kv;
        *(uint4*)&Vts[buf][sr * LD + scol] = w;
    };

    prefetch(0);
    for (int kt = 0; kt < SS; kt += 64) {
        const int buf = (kt >> 6) & 1;
        stage(buf);
        const int nk = (kt + 64 < SS) ? kt + 64 : 0;  // wrap: harmless dead load
        prefetch(nk);
        barrier_nodrain();

        // S^T = K·Q^T (exp2 domain; Q pre-scaled by 0.125*log2e)
        f32x4 st[4];
        __builtin_amdgcn_s_setprio(1);
#pragma unroll
        for (int nt = 0; nt < 4; ++nt) {
            const bf16x8 ka = *(const bf16x8*)&Ks[buf][(nt * 16 + l16) * LD + q4 * 8];
            const bf16x8 kb2 = *(const bf16x8*)&Ks[buf][(nt * 16 + l16) * LD + 32 + q4 * 8];
            f32x4 s = mfma16(ka, qf[0], fz);
            st[nt] = mfma16(kb2, qf[1], s);
        }
        __builtin_amdgcn_s_setprio(0);

        // P^T = exp2(S^T), in-register (K=16 B-frag layout)
        s16x4 p[4];
#pragma unroll
        for (int nt = 0; nt < 4; ++nt) {
#pragma unroll
            for (int r = 0; r < 4; ++r)
                p[nt][r] = (short)f2bf(__builtin_amdgcn_exp2f(st[nt][r]));
        }

        // O^T += V^T·P^T ; l via ones-MFMA (every reg = l[q=l16])
        __builtin_amdgcn_s_setprio(1);
#pragma unroll
        for (int nt = 0; nt < 4; ++nt) {
#pragma unroll
            for (int dt = 0; dt < 4; ++dt) {
                const s16x4 va =
                    *(const s16x4*)&Vts[buf][(dt * 16 + l16) * LD + ((nt * 4 + q4) ^ swV) * 4];
                ot[dt] = mfma16k16(va, p[nt], ot[dt]);
            }
            lacc = mfma16k16(onesA, p[nt], lacc);
        }
        __builtin_amdgcn_s_setprio(0);
    }

    // normalize + direct bf16 ctx write (lacc broadcast: all regs hold l[q=l16])
    {
        const float inv = 1.f / lacc[0];
        u16* Cb = Ctx + (size_t)(b * SS + q0 + l16) * D + h * 64 + q4 * 4;
#pragma unroll
        for (int dt = 0; dt < 4; ++dt) {
            s16x4 w;
#pragma unroll
            for (int r = 0; r < 4; ++r) w[r] = (short)f2bf(ot[dt][r] * inv);
            *(s16x4*)(Cb + dt * 16) = w;  // O[q][dv], dv = dt*16 + q4*4 + r
        }
    }
}

extern "C" void kernel_launch(void* const* d_in, const int* in_sizes, int n_in,
                              void* d_out, int out_size, void* d_ws, size_t ws_size,
                              hipStream_t stream) {
    const float* query = (const float*)d_in[0];
    const float* key   = (const float*)d_in[1];
    const float* value = (const float*)d_in[2];
    const float* w_q   = (const float*)d_in[3];
    const float* w_k   = (const float*)d_in[4];
    const float* w_v   = (const float*)d_in[5];
    const float* w_o   = (const float*)d_in[6];
    float* out = (float*)d_out;

    const size_t MEG = 1024 * 1024;
    if (ws_size < 32 * MEG) return;  // layout needs 32 MiB
    u16* ws = (u16*)d_ws;
    u16* Qp    = ws;
    u16* Kp    = ws + 4 * MEG;
    u16* VtAll = ws + 8 * MEG;
    u16* ctx   = ws + 12 * MEG;  // ends at 16 MEG u16 = 32 MiB

    gemm_qkv<<<dim3(256, 3), 256, 0, stream>>>(query, key, value, w_q, w_k, w_v, Qp, Kp, VtAll);
    flash_attn<<<dim3(512), 512, 0, stream>>>(Qp, Kp, VtAll, ctx);
    gemm_out<<<dim3(512), 256, 0, stream>>>(ctx, w_o, out);
}

// Round 6
// 211.990 us; speedup vs baseline: 1.1695x; 1.1399x over previous
//
#include <hip/hip_runtime.h>

typedef unsigned short u16;
typedef unsigned int u32;
typedef __bf16 bf16x8 __attribute__((ext_vector_type(8)));
typedef float f32x4 __attribute__((ext_vector_type(4)));
typedef short s16x4 __attribute__((ext_vector_type(4)));

#define AS1 __attribute__((address_space(1)))
#define AS3 __attribute__((address_space(3)))

__device__ __forceinline__ f32x4 mfma16(bf16x8 a, bf16x8 b, f32x4 c) {
    return __builtin_amdgcn_mfma_f32_16x16x32_bf16(a, b, c, 0, 0, 0);
}
// K=16 shape: B-operand layout == C/D layout (transpose-free PV)
__device__ __forceinline__ f32x4 mfma16k16(s16x4 a, s16x4 b, f32x4 c) {
    return __builtin_amdgcn_mfma_f32_16x16x16bf16_1k(a, b, c, 0, 0, 0);
}

__device__ __forceinline__ u16 f2bf(float f) {
    return __builtin_bit_cast(u16, (__bf16)f);
}

__device__ __forceinline__ void gld16(const u16* g, u16* l) {
    __builtin_amdgcn_global_load_lds((AS1 void*)g, (AS3 void*)l, 16, 0, 0);
}

// Raw barrier: drain LDS ops only; global prefetch loads stay in flight (T4).
__device__ __forceinline__ void barrier_nodrain() {
    asm volatile("s_waitcnt lgkmcnt(0)" ::: "memory");
    __builtin_amdgcn_s_barrier();
    asm volatile("" ::: "memory");
}

// ---------------- fused fp32 -> bf16 conversion ----------------
__global__ __launch_bounds__(256) void cvt_all(const float* __restrict__ q, const float* __restrict__ k,
                                               const float* __restrict__ v, const float* __restrict__ wq,
                                               const float* __restrict__ wk, const float* __restrict__ wv,
                                               const float* __restrict__ wo, u16* __restrict__ qo,
                                               u16* __restrict__ ko, u16* __restrict__ vo,
                                               u16* __restrict__ wqo, u16* __restrict__ wko,
                                               u16* __restrict__ wvo, u16* __restrict__ woo) {
    const int y = blockIdx.y;
    const float* x; u16* o; int n;
    switch (y) {
        case 0: x = q; o = qo; n = 4 << 20; break;
        case 1: x = k; o = ko; n = 4 << 20; break;
        case 2: x = v; o = vo; n = 4 << 20; break;
        case 3: x = wq; o = wqo; n = 1 << 20; break;
        case 4: x = wk; o = wko; n = 1 << 20; break;
        case 5: x = wv; o = wvo; n = 1 << 20; break;
        default: x = wo; o = woo; n = 1 << 20; break;
    }
    int i = (blockIdx.x * 256 + threadIdx.x) * 4;
    if (i >= n) return;
    float4 vv = *(const float4*)(x + i);
    u32 lo = (u32)f2bf(vv.x) | ((u32)f2bf(vv.y) << 16);
    u32 hi = (u32)f2bf(vv.z) | ((u32)f2bf(vv.w) << 16);
    *(uint2*)(o + i) = make_uint2(lo, hi);
}

// ---------------- GEMM: C[.,N] = A[.,K] @ Bt[N,K]^T ----------------
// BK=64 (was 32): halves K-steps -> halves barrier+vmcnt-drain count, the
// dominant fixed cost of the 2-sync gld16 structure (round-5 counters showed
// staging-latency-bound, not pipe-bound). LDS 32 KB (A+B single-buffered).
// Swizzle: gld16 writes linearly, so the GLOBAL source k-chunk is pre-swizzled
// (clog = cpos ^ (row&7)); reads XOR the same key -> 8 lanes per 16B slot,
// conflict-free ds_read_b128. Each 8-lane group still reads one contiguous
// 128 B global row segment (chunk permutation within the segment).
template <int BM, int BN, bool BF16OUT>
__device__ __forceinline__ void gemm_core(const u16* __restrict__ A, const u16* __restrict__ Bt,
                                          void* __restrict__ Cp, int K, int N, int m0, int n0,
                                          float oscale) {
    constexpr int WROWS = BM / 64;        // 2 (128x128) or 1 (64x128)
    constexpr int WCOLS = 4 / WROWS;      // 2 or 4
    constexpr int BFR = BN / WCOLS / 16;  // 4 or 2
    constexpr int RPWA = BM / 4;          // staging rows per wave (A)
    constexpr int RPWB = BN / 4;          // staging rows per wave (B)
    constexpr int PA = RPWA / 8, PB = RPWB / 8;
    __shared__ __align__(16) u16 As[BM * 64];
    __shared__ __align__(16) u16 Bs[BN * 64];
    const int tid = threadIdx.x;
    const int lane = tid & 63, wave = tid >> 6;
    const int l16 = lane & 15, q4 = lane >> 4;
    const int wm = (wave / WCOLS) * 64, wn = (wave % WCOLS) * (BFR * 16);

    const f32x4 fz = {0.f, 0.f, 0.f, 0.f};
    f32x4 acc[4][BFR];
#pragma unroll
    for (int i = 0; i < 4; ++i)
#pragma unroll
        for (int j = 0; j < BFR; ++j) acc[i][j] = fz;

    // staging addresses: instr (wave,p) covers 8 rows; lane -> row+ (lane>>3),
    // LDS chunk-pos (lane&7); global k-chunk = pos ^ (row&7)  [source pre-swizzle]
    const int srow = lane >> 3;                 // 0..7 == row&7 of the staged row
    const int clog = (lane & 7) ^ srow;         // swizzled global k-chunk
    const u16* Ag = A + (size_t)(m0 + wave * RPWA + srow) * K + clog * 8;
    const u16* Bg = Bt + (size_t)(n0 + wave * RPWB + srow) * K + clog * 8;
    const int rk = l16 & 7;                     // read-side swizzle key (= row&7)

    for (int k0 = 0; k0 < K; k0 += 64) {
        __syncthreads();
#pragma unroll
        for (int p = 0; p < PA; ++p)
            gld16(Ag + (size_t)(p * 8) * K + k0, As + (wave * RPWA + p * 8) * 64);
#pragma unroll
        for (int p = 0; p < PB; ++p)
            gld16(Bg + (size_t)(p * 8) * K + k0, Bs + (wave * RPWB + p * 8) * 64);
        __syncthreads();
#pragma unroll
        for (int h = 0; h < 2; ++h) {  // two K=32 halves of the 64-col tile
            const int cs = ((h * 4 + q4) ^ rk) * 8;
            bf16x8 af[4], bfr[BFR];
#pragma unroll
            for (int i = 0; i < 4; ++i)
                af[i] = *(const bf16x8*)&As[(wm + i * 16 + l16) * 64 + cs];
#pragma unroll
            for (int j = 0; j < BFR; ++j)
                bfr[j] = *(const bf16x8*)&Bs[(wn + j * 16 + l16) * 64 + cs];
#pragma unroll
            for (int i = 0; i < 4; ++i)
#pragma unroll
                for (int j = 0; j < BFR; ++j) acc[i][j] = mfma16(af[i], bfr[j], acc[i][j]);
        }
    }

#pragma unroll
    for (int i = 0; i < 4; ++i) {
        const int row = m0 + wm + i * 16 + q4 * 4;
#pragma unroll
        for (int j = 0; j < BFR; ++j) {
            const int col = n0 + wn + j * 16 + l16;
#pragma unroll
            for (int r = 0; r < 4; ++r) {
                const float vr = acc[i][j][r] * oscale;
                if constexpr (BF16OUT)
                    ((u16*)Cp)[(size_t)(row + r) * N + col] = f2bf(vr);
                else
                    ((float*)Cp)[(size_t)(row + r) * N + col] = vr;
            }
        }
    }
}

// z=0: Q = query@wq^T (pre-scaled by 0.125*log2e); z=1: K = key@wk^T;
// z=2: Vt = wv @ value^T -> VtAll[h*64+dv][b*2048+s]
// T1: XCD-aware swizzle for z in {0,1}: XCD c gets 32 contiguous tiles
// (4 A-panels x all 8 B-panels -> ~3 MB working set, fits 4 MB L2).
__global__ __launch_bounds__(256) void gemm_qkv(const u16* __restrict__ qb, const u16* __restrict__ kb,
                                                const u16* __restrict__ vb, const u16* __restrict__ wqb,
                                                const u16* __restrict__ wkb, const u16* __restrict__ wvb,
                                                u16* __restrict__ Qp, u16* __restrict__ Kp,
                                                u16* __restrict__ VtAll) {
    const int z = blockIdx.y;
    int x = blockIdx.x;
    if (z != 2) x = (x & 7) * 32 + (x >> 3);  // bijective: 256 % 8 == 0
    const u16 *A, *Bt;
    u16* C;
    int N, m0, n0;
    float sc = 1.0f;
    if (z == 0) {
        A = qb; Bt = wqb; C = Qp; N = 1024; m0 = (x >> 3) * 128; n0 = (x & 7) * 128;
        sc = 0.18033688011112042f;  // (1/sqrt(64)) * log2(e)
    } else if (z == 1) {
        A = kb; Bt = wkb; C = Kp; N = 1024; m0 = (x >> 3) * 128; n0 = (x & 7) * 128;
    } else {
        A = wvb; Bt = vb; C = VtAll; N = 4096; m0 = (x >> 5) * 128; n0 = (x & 31) * 128;
    }
    gemm_core<128, 128, true>(A, Bt, C, 1024, N, m0, n0, sc);
}

__global__ __launch_bounds__(256) void gemm_out(const u16* __restrict__ ctx,
                                                const u16* __restrict__ wob,
                                                float* __restrict__ out) {
    // T1 swizzle: XCD c gets 64 contiguous tiles (8 m-panels x all 8 n)
    const int xo = (blockIdx.x & 7) * 64 + (blockIdx.x >> 3);  // bijective: 512 % 8 == 0
    gemm_core<64, 128, false>(ctx, wob, out, 1024, 1024, (xo >> 3) * 64, (xo & 7) * 128, 1.0f);
}

// ---------------- Flash attention: 8 waves x 16 q-rows (round-3 winner, verbatim) ----
// 512 threads/block, wave owns 16 q-rows. 2 blocks/CU x 8 waves = 4 waves/SIMD.
// Per-tile: stage(buf from regs) -> prefetch(next into regs) -> barrier_nodrain
// (lgkm only; prefetch stays in flight, T4/T14) -> QK, exp, PV.
// Buffer safety: iter t writes buf t&1, last read in compute(t-2), separated by
// barrier(t-1) which every wave passes only after finishing compute(t-2).
// T1: 1D grid + swizzle so each XCD owns 4 whole (h,b) groups -> K/V fetched
// once per XCD (KV+Q working set 3 MB < 4 MB L2). Measured: 56.9 us, MfmaUtil 43.
__global__ __launch_bounds__(512, 4) void flash_attn(const u16* __restrict__ Qp,
                                                     const u16* __restrict__ Kp,
                                                     const u16* __restrict__ VtAll,
                                                     u16* __restrict__ Ctx) {
    constexpr int D = 1024, SS = 2048, LD = 72;
    __shared__ __align__(16) u16 Ks[2][64 * LD];   // [buf][s_row][dk]
    __shared__ __align__(16) u16 Vts[2][64 * LD];  // [buf][dv][s], 8B sub-chunk swizzled

    const int tid = threadIdx.x;
    const int lane = tid & 63, wave = tid >> 6;  // 8 waves
    const int l16 = lane & 15, q4 = lane >> 4;

    const int nb = blockIdx.x;                    // 512 blocks, 1D
    const int orig = (nb & 7) * 64 + (nb >> 3);   // bijective: 512 % 8 == 0
    const int h = (orig >> 4) & 15, b = orig >> 8;
    const int q0 = (orig & 15) * 128 + wave * 16;

    bf16x8 qf[2];
    {
        const u16* Qb = Qp + (size_t)(b * SS + q0 + l16) * D + h * 64;
        qf[0] = *(const bf16x8*)(Qb + q4 * 8);
        qf[1] = *(const bf16x8*)(Qb + 32 + q4 * 8);
    }

    const f32x4 fz = {0.f, 0.f, 0.f, 0.f};
    f32x4 ot[4], lacc = fz;
#pragma unroll
    for (int dt = 0; dt < 4; ++dt) ot[dt] = fz;

    s16x4 onesA;
    onesA[0] = onesA[1] = onesA[2] = onesA[3] = (short)0x3F80;  // bf16 1.0

    // staging: 512 threads x one uint4 each covers a full 64x64 bf16 tile
    const int sr = tid >> 3;           // 0..63
    const int scol = (tid & 7) * 8;    // 8-elem (16B) chunk
    const int vswap = (sr >> 3) & 1;   // == (dv>>3)&1 for the staged row
    const int swV = (l16 >> 3) & 1;    // read-side sub-chunk swizzle key
    const u16* Kg = Kp + (size_t)(b * SS + sr) * D + h * 64 + scol;
    const u16* Vg = VtAll + (size_t)(h * 64 + sr) * 4096 + b * SS + scol;

    uint4 kv, vv;
    auto prefetch = [&](int kt) {
        kv = *(const uint4*)(Kg + (size_t)kt * D);
        vv = *(const uint4*)(Vg + kt);
    };
    auto stage = [&](int buf) {
        uint4 w = vswap ? make_uint4(vv.z, vv.w, vv.x, vv.y) : vv;  // 8B-half swap
        *(uint4*)&Ks[buf][sr * LD + scol] = kv;
        *(uint4*)&Vts[buf][sr * LD + scol] = w;
    };

    prefetch(0);
    for (int kt = 0; kt < SS; kt += 64) {
        const int buf = (kt >> 6) & 1;
        stage(buf);
        const int nk = (kt + 64 < SS) ? kt + 64 : 0;  // wrap: harmless dead load
        prefetch(nk);
        barrier_nodrain();

        // S^T = K·Q^T (exp2 domain; Q pre-scaled by 0.125*log2e)
        f32x4 st[4];
        __builtin_amdgcn_s_setprio(1);
#pragma unroll
        for (int nt = 0; nt < 4; ++nt) {
            const bf16x8 ka = *(const bf16x8*)&Ks[buf][(nt * 16 + l16) * LD + q4 * 8];
            const bf16x8 kb2 = *(const bf16x8*)&Ks[buf][(nt * 16 + l16) * LD + 32 + q4 * 8];
            f32x4 s = mfma16(ka, qf[0], fz);
            st[nt] = mfma16(kb2, qf[1], s);
        }
        __builtin_amdgcn_s_setprio(0);

        // P^T = exp2(S^T), in-register (K=16 B-frag layout)
        s16x4 p[4];
#pragma unroll
        for (int nt = 0; nt < 4; ++nt) {
#pragma unroll
            for (int r = 0; r < 4; ++r)
                p[nt][r] = (short)f2bf(__builtin_amdgcn_exp2f(st[nt][r]));
        }

        // O^T += V^T·P^T ; l via ones-MFMA (every reg = l[q=l16])
        __builtin_amdgcn_s_setprio(1);
#pragma unroll
        for (int nt = 0; nt < 4; ++nt) {
#pragma unroll
            for (int dt = 0; dt < 4; ++dt) {
                const s16x4 va =
                    *(const s16x4*)&Vts[buf][(dt * 16 + l16) * LD + ((nt * 4 + q4) ^ swV) * 4];
                ot[dt] = mfma16k16(va, p[nt], ot[dt]);
            }
            lacc = mfma16k16(onesA, p[nt], lacc);
        }
        __builtin_amdgcn_s_setprio(0);
    }

    // normalize + direct bf16 ctx write (lacc broadcast: all regs hold l[q=l16])
    {
        const float inv = 1.f / lacc[0];
        u16* Cb = Ctx + (size_t)(b * SS + q0 + l16) * D + h * 64 + q4 * 4;
#pragma unroll
        for (int dt = 0; dt < 4; ++dt) {
            s16x4 w;
#pragma unroll
            for (int r = 0; r < 4; ++r) w[r] = (short)f2bf(ot[dt][r] * inv);
            *(s16x4*)(Cb + dt * 16) = w;  // O[q][dv], dv = dt*16 + q4*4 + r
        }
    }
}

extern "C" void kernel_launch(void* const* d_in, const int* in_sizes, int n_in,
                              void* d_out, int out_size, void* d_ws, size_t ws_size,
                              hipStream_t stream) {
    const float* query = (const float*)d_in[0];
    const float* key   = (const float*)d_in[1];
    const float* value = (const float*)d_in[2];
    const float* w_q   = (const float*)d_in[3];
    const float* w_k   = (const float*)d_in[4];
    const float* w_v   = (const float*)d_in[5];
    const float* w_o   = (const float*)d_in[6];
    float* out = (float*)d_out;

    const size_t MEG = 1024 * 1024;
    if (ws_size < 64 * MEG) return;  // layout needs 64 MiB
    u16* ws = (u16*)d_ws;
    u16* qb    = ws;
    u16* kb    = ws + 4 * MEG;
    u16* vb    = ws + 8 * MEG;
    u16* wqb   = ws + 12 * MEG;
    u16* wkb   = ws + 13 * MEG;
    u16* wvb   = ws + 14 * MEG;
    u16* wob   = ws + 15 * MEG;  // live until gemm_out
    u16* Qp    = ws + 16 * MEG;
    u16* Kp    = ws + 20 * MEG;
    u16* VtAll = ws + 24 * MEG;
    u16* ctx   = ws + 28 * MEG;  // ends at 32 MEG u16 = 64 MiB

    cvt_all<<<dim3(4096, 7), 256, 0, stream>>>(query, key, value, w_q, w_k, w_v, w_o,
                                               qb, kb, vb, wqb, wkb, wvb, wob);
    gemm_qkv<<<dim3(256, 3), 256, 0, stream>>>(qb, kb, vb, wqb, wkb, wvb, Qp, Kp, VtAll);
    flash_attn<<<dim3(512), 512, 0, stream>>>(Qp, Kp, VtAll, ctx);
    gemm_out<<<dim3(512), 256, 0, stream>>>(ctx, wob, out);
}